// Round 1
// baseline (268.993 us; speedup 1.0000x reference)
//
#include <hip/hip_runtime.h>
#include <cstdint>
#include <cstddef>

#define D_MODEL 1024
#define NHEADS  16
#define DK      64
#define BATCH   2
#define SEQ     2048
#define MTOT    (BATCH*SEQ)   // 4096

typedef unsigned short u16;
typedef __attribute__((ext_vector_type(8))) __bf16 bf16x8;
typedef __attribute__((ext_vector_type(4))) float  f32x4;

static __device__ __forceinline__ u16 f2bf(float f) {
  union { float f; uint32_t u; } v; v.f = f;
  uint32_t u = v.u;
  u += 0x7fffu + ((u >> 16) & 1u);   // round-to-nearest-even
  return (u16)(u >> 16);
}

static __device__ __forceinline__ void gload16(const void* g, void* l) {
  __builtin_amdgcn_global_load_lds((const __attribute__((address_space(1))) void*)g,
                                   (__attribute__((address_space(3))) void*)l,
                                   16, 0, 0);
}

// ---------------- fp32 -> bf16 cast ----------------
__global__ void cast_bf16_kernel(const float* __restrict__ in, u16* __restrict__ out, int n) {
  int i = (blockIdx.x * blockDim.x + threadIdx.x) * 4;
  if (i >= n) return;
  float4 f = *reinterpret_cast<const float4*>(in + i);
  ushort4 o;
  o.x = f2bf(f.x); o.y = f2bf(f.y); o.z = f2bf(f.z); o.w = f2bf(f.w);
  *reinterpret_cast<ushort4*>(out + i) = o;
}

// ---------------- GEMM: C = A @ Bt^T + bias ----------------
// A [M=4096, K=1024] bf16 row-major; Bt [N=1024, K=1024] bf16 row-major (torch W layout).
// MODE 0: write bf16 to q/k head layout [B,H,S,DK]
// MODE 1: write bf16 to v^T head layout [B,H,DK,S]
// MODE 2: write fp32 to [M,N] (final output)
template<int MODE>
__global__ __launch_bounds__(256, 2) void gemm_bt(
    const u16* __restrict__ A, const u16* __restrict__ Bt,
    const float* __restrict__ bias, void* __restrict__ outp) {
  constexpr int K = 1024, N = 1024;
  __shared__ __align__(16) u16 lA[128 * 64];
  __shared__ __align__(16) u16 lB[128 * 64];
  const int w = threadIdx.x >> 6, lane = threadIdx.x & 63;
  const int blockM = blockIdx.x * 128, blockN = blockIdx.y * 128;
  const int wm = (w >> 1) * 64, wn = (w & 1) * 64;
  f32x4 acc[4][4] = {};
  for (int kt = 0; kt < K; kt += 64) {
#pragma unroll
    for (int it = 0; it < 4; ++it) {
      int rowb = w * 32 + it * 8;
      int row  = rowb + (lane >> 3);
      int cc   = (lane & 7) * 8;
      gload16(A  + (size_t)(blockM + row) * K + kt + cc, &lA[rowb * 64]);
      gload16(Bt + (size_t)(blockN + row) * K + kt + cc, &lB[rowb * 64]);
    }
    __syncthreads();
#pragma unroll
    for (int kc = 0; kc < 2; ++kc) {
      bf16x8 af[4], bfr[4];
#pragma unroll
      for (int i = 0; i < 4; ++i)
        af[i] = *(const bf16x8*)&lA[(wm + i * 16 + (lane & 15)) * 64 + kc * 32 + (lane >> 4) * 8];
#pragma unroll
      for (int j = 0; j < 4; ++j)
        bfr[j] = *(const bf16x8*)&lB[(wn + j * 16 + (lane & 15)) * 64 + kc * 32 + (lane >> 4) * 8];
#pragma unroll
      for (int i = 0; i < 4; ++i)
#pragma unroll
        for (int j = 0; j < 4; ++j)
          acc[i][j] = __builtin_amdgcn_mfma_f32_16x16x32_bf16(af[i], bfr[j], acc[i][j], 0, 0, 0);
    }
    __syncthreads();
  }
  // epilogue: D layout col = lane&15, row = (lane>>4)*4 + r
#pragma unroll
  for (int i = 0; i < 4; ++i)
#pragma unroll
    for (int j = 0; j < 4; ++j)
#pragma unroll
      for (int r = 0; r < 4; ++r) {
        int m = blockM + wm + i * 16 + (lane >> 4) * 4 + r;
        int n = blockN + wn + j * 16 + (lane & 15);
        float val = acc[i][j][r] + bias[n];
        if (MODE == 2) {
          ((float*)outp)[(size_t)m * N + n] = val;
        } else {
          int b = m >> 11, s = m & (SEQ - 1), h = n >> 6, d = n & (DK - 1);
          u16 bv = f2bf(val);
          if (MODE == 0)
            ((u16*)outp)[(((size_t)(b * NHEADS + h)) * SEQ + s) * DK + d] = bv;
          else
            ((u16*)outp)[(((size_t)(b * NHEADS + h)) * DK + d) * SEQ + s] = bv;
        }
      }
}

// ---------------- causal flash attention ----------------
// qh,kh: [B,H,S,DK] bf16; vt: [B,H,DK,S] bf16; out attnb: [B,S,D_MODEL] bf16
__global__ __launch_bounds__(256, 2) void attn_kernel(
    const u16* __restrict__ qh, const u16* __restrict__ kh,
    const u16* __restrict__ vt, u16* __restrict__ attnb) {
  const int qt = blockIdx.x, bh = blockIdx.y;
  const int qbase = qt * 64;
  __shared__ __align__(16) u16 lQ[64 * 64];
  __shared__ __align__(16) u16 lK[64 * 64];
  __shared__ __align__(16) u16 lVt[64 * 64];
  __shared__ __align__(16) u16 lP[4][16 * 64];
  const int w = threadIdx.x >> 6, lane = threadIdx.x & 63;
  const u16* qp = qh + (size_t)bh * SEQ * DK;
  const u16* kp = kh + (size_t)bh * SEQ * DK;
  const u16* vp = vt + (size_t)bh * DK * SEQ;

  // stage Q tile [64][64]
#pragma unroll
  for (int it = 0; it < 2; ++it) {
    int rowb = w * 16 + it * 8;
    gload16(qp + (size_t)(qbase + rowb + (lane >> 3)) * DK + (lane & 7) * 8, &lQ[rowb * 64]);
  }
  __syncthreads();
  bf16x8 aq[2];
#pragma unroll
  for (int kc = 0; kc < 2; ++kc)
    aq[kc] = *(const bf16x8*)&lQ[(w * 16 + (lane & 15)) * 64 + kc * 32 + (lane >> 4) * 8];

  float m_run[4], l_run[4];
  f32x4 oacc[4] = {};
#pragma unroll
  for (int r = 0; r < 4; ++r) { m_run[r] = -1e30f; l_run[r] = 0.f; }

  const int nt = qt + 1;
  for (int t = 0; t < nt; ++t) {
    const int j0 = t * 64;
    __syncthreads();   // prev iteration's LDS reads done before overwrite
#pragma unroll
    for (int it = 0; it < 2; ++it) {
      int rowb = w * 16 + it * 8;
      gload16(kp + (size_t)(j0 + rowb + (lane >> 3)) * DK + (lane & 7) * 8, &lK[rowb * 64]);
      gload16(vp + (size_t)(rowb + (lane >> 3)) * SEQ + j0 + (lane & 7) * 8, &lVt[rowb * 64]);
    }
    __syncthreads();

    // S = Q K^T : D col = j (lane&15 within nb block), row = q-row
    f32x4 sacc[4] = {};
#pragma unroll
    for (int kc = 0; kc < 2; ++kc)
#pragma unroll
      for (int nb = 0; nb < 4; ++nb) {
        bf16x8 kf = *(const bf16x8*)&lK[(nb * 16 + (lane & 15)) * 64 + kc * 32 + (lane >> 4) * 8];
        sacc[nb] = __builtin_amdgcn_mfma_f32_16x16x32_bf16(aq[kc], kf, sacc[nb], 0, 0, 0);
      }
    const bool diag = (j0 == qbase);
#pragma unroll
    for (int nb = 0; nb < 4; ++nb)
#pragma unroll
      for (int r = 0; r < 4; ++r) {
        float s = sacc[nb][r] * 0.125f;
        if (diag) {
          int jg = j0 + nb * 16 + (lane & 15);
          int ig = qbase + w * 16 + (lane >> 4) * 4 + r;
          if (jg > ig) s = -1e30f;
        }
        sacc[nb][r] = s;
      }
    // online softmax stats per q-row r
    float alpha[4];
#pragma unroll
    for (int r = 0; r < 4; ++r) {
      float mx = fmaxf(fmaxf(sacc[0][r], sacc[1][r]), fmaxf(sacc[2][r], sacc[3][r]));
#pragma unroll
      for (int msk = 1; msk < 16; msk <<= 1) mx = fmaxf(mx, __shfl_xor(mx, msk));
      float mn = fmaxf(m_run[r], mx);
      alpha[r] = __expf(m_run[r] - mn);
      m_run[r] = mn;
      float rs = 0.f;
#pragma unroll
      for (int nb = 0; nb < 4; ++nb) {
        float e = __expf(sacc[nb][r] - mn);
        sacc[nb][r] = e;
        rs += e;
      }
#pragma unroll
      for (int msk = 1; msk < 16; msk <<= 1) rs += __shfl_xor(rs, msk);
      l_run[r] = l_run[r] * alpha[r] + rs;
    }
    // P -> per-wave LDS (transpose to A-operand layout)
#pragma unroll
    for (int nb = 0; nb < 4; ++nb)
#pragma unroll
      for (int r = 0; r < 4; ++r)
        lP[w][((lane >> 4) * 4 + r) * 64 + nb * 16 + (lane & 15)] = f2bf(sacc[nb][r]);
    // rescale O
#pragma unroll
    for (int nd = 0; nd < 4; ++nd)
#pragma unroll
      for (int r = 0; r < 4; ++r) oacc[nd][r] *= alpha[r];
    // O += P @ V  (B-operand from v^T tile)
#pragma unroll
    for (int jc = 0; jc < 2; ++jc) {
      bf16x8 pa = *(const bf16x8*)&lP[w][(lane & 15) * 64 + jc * 32 + (lane >> 4) * 8];
#pragma unroll
      for (int nd = 0; nd < 4; ++nd) {
        bf16x8 vf = *(const bf16x8*)&lVt[(nd * 16 + (lane & 15)) * 64 + jc * 32 + (lane >> 4) * 8];
        oacc[nd] = __builtin_amdgcn_mfma_f32_16x16x32_bf16(pa, vf, oacc[nd], 0, 0, 0);
      }
    }
  }
  // epilogue: attnb[b, s, h*64+d]
  const int b = bh >> 4, h = bh & 15;
#pragma unroll
  for (int nd = 0; nd < 4; ++nd)
#pragma unroll
    for (int r = 0; r < 4; ++r) {
      int s = qbase + w * 16 + (lane >> 4) * 4 + r;
      int d = nd * 16 + (lane & 15);
      float val = oacc[nd][r] / l_run[r];
      attnb[((size_t)(b * SEQ + s)) * D_MODEL + h * 64 + d] = f2bf(val);
    }
}

// ---------------- launcher ----------------
extern "C" void kernel_launch(void* const* d_in, const int* in_sizes, int n_in,
                              void* d_out, int out_size, void* d_ws, size_t ws_size,
                              hipStream_t stream) {
  (void)in_sizes; (void)n_in; (void)out_size; (void)ws_size;
  const float* Q  = (const float*)d_in[0];
  const float* K  = (const float*)d_in[1];
  const float* V  = (const float*)d_in[2];
  // d_in[3] = mask (causal triu) — implemented analytically
  const float* Wq = (const float*)d_in[4];
  const float* bq = (const float*)d_in[5];
  const float* Wk = (const float*)d_in[6];
  const float* bk = (const float*)d_in[7];
  const float* Wv = (const float*)d_in[8];
  const float* bv = (const float*)d_in[9];
  const float* Wo = (const float*)d_in[10];
  const float* bo = (const float*)d_in[11];

  char* ws = (char*)d_ws;
  size_t off = 0;
  auto carve = [&](size_t bytes) { char* p = ws + off; off += bytes; return p; };
  const size_t szX = (size_t)MTOT * D_MODEL * 2;       // 8 MB
  const size_t szW = (size_t)D_MODEL * D_MODEL * 2;    // 2 MB
  u16* Qb  = (u16*)carve(szX);
  u16* Kb  = (u16*)carve(szX);
  u16* Vb  = (u16*)carve(szX);
  u16* Wqb = (u16*)carve(szW);
  u16* Wkb = (u16*)carve(szW);
  u16* Wvb = (u16*)carve(szW);
  u16* Wob = (u16*)carve(szW);
  u16* qhB = (u16*)carve(szX);
  u16* khB = (u16*)carve(szX);
  u16* vtB = (u16*)carve(szX);
  u16* attnb = Qb;   // Qb is dead after the q-projection GEMM

  const int nX = MTOT * D_MODEL;       // 4194304
  const int nW = D_MODEL * D_MODEL;    // 1048576
  cast_bf16_kernel<<<nX / 1024, 256, 0, stream>>>(Q,  Qb,  nX);
  cast_bf16_kernel<<<nX / 1024, 256, 0, stream>>>(K,  Kb,  nX);
  cast_bf16_kernel<<<nX / 1024, 256, 0, stream>>>(V,  Vb,  nX);
  cast_bf16_kernel<<<nW / 1024, 256, 0, stream>>>(Wq, Wqb, nW);
  cast_bf16_kernel<<<nW / 1024, 256, 0, stream>>>(Wk, Wkb, nW);
  cast_bf16_kernel<<<nW / 1024, 256, 0, stream>>>(Wv, Wvb, nW);
  cast_bf16_kernel<<<nW / 1024, 256, 0, stream>>>(Wo, Wob, nW);

  dim3 gg(MTOT / 128, D_MODEL / 128);
  gemm_bt<0><<<gg, 256, 0, stream>>>(Qb, Wqb, bq, qhB);
  gemm_bt<0><<<gg, 256, 0, stream>>>(Kb, Wkb, bk, khB);
  gemm_bt<1><<<gg, 256, 0, stream>>>(Vb, Wvb, bv, vtB);

  attn_kernel<<<dim3(SEQ / 64, BATCH * NHEADS), 256, 0, stream>>>(qhB, khB, vtB, attnb);

  gemm_bt<2><<<gg, 256, 0, stream>>>(attnb, Wob, bo, d_out);
}

// Round 2
// 147.009 us; speedup vs baseline: 1.8298x; 1.8298x over previous
//
#include <hip/hip_runtime.h>
#include <cstdint>
#include <cstddef>

#define D_MODEL 1024
#define NHEADS  16
#define DK      64
#define BATCH   2
#define SEQ     2048
#define MTOT    (BATCH*SEQ)   // 4096
#define NT      (SEQ/64)      // 32

typedef unsigned short u16;
typedef __attribute__((ext_vector_type(8))) __bf16 bf16x8;
typedef __attribute__((ext_vector_type(4))) float  f32x4;
typedef __attribute__((ext_vector_type(4))) uint32_t u32x4;

static __device__ __forceinline__ u16 f2bf(float f) {
  union { float f; uint32_t u; } v; v.f = f;
  uint32_t u = v.u;
  u += 0x7fffu + ((u >> 16) & 1u);   // round-to-nearest-even
  return (u16)(u >> 16);
}

static __device__ __forceinline__ void gload16(const void* g, void* l) {
  __builtin_amdgcn_global_load_lds((const __attribute__((address_space(1))) void*)g,
                                   (__attribute__((address_space(3))) void*)l,
                                   16, 0, 0);
}

// ---------------- fp32 -> bf16 cast ----------------
__global__ void cast_bf16_kernel(const float* __restrict__ in, u16* __restrict__ out, int n) {
  int i = (blockIdx.x * blockDim.x + threadIdx.x) * 4;
  if (i >= n) return;
  float4 f = *reinterpret_cast<const float4*>(in + i);
  ushort4 o;
  o.x = f2bf(f.x); o.y = f2bf(f.y); o.z = f2bf(f.z); o.w = f2bf(f.w);
  *reinterpret_cast<ushort4*>(out + i) = o;
}

// ---------------- fused QKV projection GEMM ----------------
// A = [Qb|Kb|Vb] stacked: [3*4096, 1024] bf16. W sel by m-chunk.
// q,k -> [B,H,S,DK]; v -> [B,H,DK,S].
__global__ __launch_bounds__(256, 2) void gemm_qkv(
    const u16* __restrict__ A,
    const u16* __restrict__ W0, const u16* __restrict__ W1, const u16* __restrict__ W2,
    const float* __restrict__ b0, const float* __restrict__ b1, const float* __restrict__ b2,
    u16* __restrict__ out_q, u16* __restrict__ out_k, u16* __restrict__ out_v) {
  constexpr int K = 1024;
  __shared__ __align__(16) u16 lA[128 * 64];
  __shared__ __align__(16) u16 lB[128 * 64];
  const int w = threadIdx.x >> 6, lane = threadIdx.x & 63;
  const int blockM = blockIdx.x * 128, blockN = blockIdx.y * 128;
  const int sel = blockIdx.x >> 5;   // 0:q 1:k 2:v (32 blocks per 4096 rows)
  const u16*  Bt   = sel == 0 ? W0 : (sel == 1 ? W1 : W2);
  const float* bias = sel == 0 ? b0 : (sel == 1 ? b1 : b2);
  const int wm = (w >> 1) * 64, wn = (w & 1) * 64;
  f32x4 acc[4][4] = {};
  for (int kt = 0; kt < K; kt += 64) {
#pragma unroll
    for (int it = 0; it < 4; ++it) {
      int rowb = w * 32 + it * 8;
      int row  = rowb + (lane >> 3);
      int cc   = (lane & 7) * 8;
      gload16(A  + (size_t)(blockM + row) * K + kt + cc, &lA[rowb * 64]);
      gload16(Bt + (size_t)(blockN + row) * K + kt + cc, &lB[rowb * 64]);
    }
    __syncthreads();
#pragma unroll
    for (int kc = 0; kc < 2; ++kc) {
      bf16x8 af[4], bfr[4];
#pragma unroll
      for (int i = 0; i < 4; ++i)
        af[i] = *(const bf16x8*)&lA[(wm + i * 16 + (lane & 15)) * 64 + kc * 32 + (lane >> 4) * 8];
#pragma unroll
      for (int j = 0; j < 4; ++j)
        bfr[j] = *(const bf16x8*)&lB[(wn + j * 16 + (lane & 15)) * 64 + kc * 32 + (lane >> 4) * 8];
#pragma unroll
      for (int i = 0; i < 4; ++i)
#pragma unroll
        for (int j = 0; j < 4; ++j)
          acc[i][j] = __builtin_amdgcn_mfma_f32_16x16x32_bf16(af[i], bfr[j], acc[i][j], 0, 0, 0);
    }
    __syncthreads();
  }
  u16* outqk = sel ? out_k : out_q;
#pragma unroll
  for (int i = 0; i < 4; ++i)
#pragma unroll
    for (int j = 0; j < 4; ++j)
#pragma unroll
      for (int r = 0; r < 4; ++r) {
        int m = blockM + wm + i * 16 + (lane >> 4) * 4 + r;
        int n = blockN + wn + j * 16 + (lane & 15);
        float val = acc[i][j][r] + bias[n];
        int ml = m & (MTOT - 1);
        int b = ml >> 11, s = ml & (SEQ - 1), h = n >> 6, d = n & (DK - 1);
        u16 bv = f2bf(val);
        if (sel == 2)
          out_v[(((size_t)(b * NHEADS + h)) * DK + d) * SEQ + s] = bv;
        else
          outqk[(((size_t)(b * NHEADS + h)) * SEQ + s) * DK + d] = bv;
      }
}

// ---------------- output projection GEMM (fp32 out) ----------------
__global__ __launch_bounds__(256, 2) void gemm_out(
    const u16* __restrict__ A, const u16* __restrict__ Bt,
    const float* __restrict__ bias, float* __restrict__ outp) {
  constexpr int K = 1024, N = 1024;
  __shared__ __align__(16) u16 lA[128 * 64];
  __shared__ __align__(16) u16 lB[128 * 64];
  const int w = threadIdx.x >> 6, lane = threadIdx.x & 63;
  const int blockM = blockIdx.x * 128, blockN = blockIdx.y * 128;
  const int wm = (w >> 1) * 64, wn = (w & 1) * 64;
  f32x4 acc[4][4] = {};
  for (int kt = 0; kt < K; kt += 64) {
#pragma unroll
    for (int it = 0; it < 4; ++it) {
      int rowb = w * 32 + it * 8;
      int row  = rowb + (lane >> 3);
      int cc   = (lane & 7) * 8;
      gload16(A  + (size_t)(blockM + row) * K + kt + cc, &lA[rowb * 64]);
      gload16(Bt + (size_t)(blockN + row) * K + kt + cc, &lB[rowb * 64]);
    }
    __syncthreads();
#pragma unroll
    for (int kc = 0; kc < 2; ++kc) {
      bf16x8 af[4], bfr[4];
#pragma unroll
      for (int i = 0; i < 4; ++i)
        af[i] = *(const bf16x8*)&lA[(wm + i * 16 + (lane & 15)) * 64 + kc * 32 + (lane >> 4) * 8];
#pragma unroll
      for (int j = 0; j < 4; ++j)
        bfr[j] = *(const bf16x8*)&lB[(wn + j * 16 + (lane & 15)) * 64 + kc * 32 + (lane >> 4) * 8];
#pragma unroll
      for (int i = 0; i < 4; ++i)
#pragma unroll
        for (int j = 0; j < 4; ++j)
          acc[i][j] = __builtin_amdgcn_mfma_f32_16x16x32_bf16(af[i], bfr[j], acc[i][j], 0, 0, 0);
    }
    __syncthreads();
  }
#pragma unroll
  for (int i = 0; i < 4; ++i)
#pragma unroll
    for (int j = 0; j < 4; ++j)
#pragma unroll
      for (int r = 0; r < 4; ++r) {
        int m = blockM + wm + i * 16 + (lane >> 4) * 4 + r;
        int n = blockN + wn + j * 16 + (lane & 15);
        outp[(size_t)m * N + n] = acc[i][j][r] + bias[n];
      }
}

// ---------------- causal flash attention (swapped QK^T, swizzled LDS) ----------------
// Staging writes linear LDS; global source pre-swizzled; reads apply chunk^(row&7).
static __device__ __forceinline__ void stage_kv(
    const u16* kp, const u16* vp, int j0,
    u16* bufK, u16* bufV, int w, int lane) {
  const int rsub = lane >> 3;                 // 0..7
  const int cl = ((lane & 7) ^ rsub) << 3;    // pre-swizzled chunk, u16 units
#pragma unroll
  for (int it = 0; it < 2; ++it) {
    const int rowb = w * 16 + it * 8;
    gload16(kp + (size_t)(j0 + rowb + rsub) * DK + cl, bufK + rowb * 64);
    gload16(vp + (size_t)(rowb + rsub) * SEQ + j0 + cl, bufV + rowb * 64);
  }
}

__global__ __launch_bounds__(256, 4) void attn_kernel(
    const u16* __restrict__ qh, const u16* __restrict__ kh,
    const u16* __restrict__ vt, u16* __restrict__ attnb) {
  __shared__ __align__(16) u16 lKV[2][2][64 * 64];   // [dbuf][K/V] = 32 KiB
  const int w = threadIdx.x >> 6, lane = threadIdx.x & 63;
  const int g = lane >> 4, q15 = lane & 15;
  const int bh = blockIdx.y;
  const int b = bh >> 4, h = bh & 15;
  const u16* qp = qh + (size_t)bh * SEQ * DK;
  const u16* kp = kh + (size_t)bh * SEQ * DK;
  const u16* vp = vt + (size_t)bh * DK * SEQ;

  for (int pi = 0; pi < 2; ++pi) {
    const int qt = pi ? (NT - 1 - blockIdx.x) : blockIdx.x;   // paired: work = 33 tiles/block
    const int qbase = qt * 64;
    const int qrow = qbase + w * 16 + q15;    // this lane's q-row (lane-local softmax)
    bf16x8 aq[2];
    const u16* qr = qp + (size_t)qrow * DK;
#pragma unroll
    for (int kc = 0; kc < 2; ++kc)
      aq[kc] = *(const bf16x8*)(qr + kc * 32 + g * 8);

    float m_run = -1e30f, l_run = 0.f;
    f32x4 oacc[4] = {};
    const int nt = qt + 1;
    __syncthreads();                          // LDS safe to overwrite (pass boundary)
    stage_kv(kp, vp, 0, lKV[0][0], lKV[0][1], w, lane);

    for (int t = 0; t < nt; ++t) {
      __syncthreads();                        // drains vmcnt -> tile t staged; buf cur^1 free
      const int cur = t & 1;
      if (t + 1 < nt)
        stage_kv(kp, vp, (t + 1) * 64, lKV[cur ^ 1][0], lKV[cur ^ 1][1], w, lane);
      const u16* bK = lKV[cur][0];
      const u16* bV = lKV[cur][1];

      // S^T = K Q^T : lane holds col q = q15, rows j = nb*16 + g*4 + r
      f32x4 sacc[4] = {};
      __builtin_amdgcn_s_setprio(1);
#pragma unroll
      for (int kc = 0; kc < 2; ++kc)
#pragma unroll
        for (int nb = 0; nb < 4; ++nb) {
          const int rr = nb * 16 + q15;
          const int cc = kc * 4 + g;
          bf16x8 kf = *(const bf16x8*)&bK[rr * 64 + ((cc ^ (rr & 7)) << 3)];
          sacc[nb] = __builtin_amdgcn_mfma_f32_16x16x32_bf16(kf, aq[kc], sacc[nb], 0, 0, 0);
        }
      __builtin_amdgcn_s_setprio(0);

      // lane-local online softmax over this lane's 16 j-values (+2 shfl across j-quads)
      const bool diag = (t == qt);
      float pv[4][4];
      float mx = -1e30f;
#pragma unroll
      for (int nb = 0; nb < 4; ++nb)
#pragma unroll
        for (int r = 0; r < 4; ++r) {
          float s = sacc[nb][r] * 0.125f;
          if (diag && (t * 64 + nb * 16 + g * 4 + r > qrow)) s = -1e30f;
          pv[nb][r] = s;
          mx = fmaxf(mx, s);
        }
      mx = fmaxf(mx, __shfl_xor(mx, 16));
      mx = fmaxf(mx, __shfl_xor(mx, 32));
      const float mn = fmaxf(m_run, mx);
      const float alpha = __expf(m_run - mn);
      m_run = mn;
      float rs = 0.f;
#pragma unroll
      for (int nb = 0; nb < 4; ++nb)
#pragma unroll
        for (int r = 0; r < 4; ++r) {
          float e = __expf(pv[nb][r] - mn);
          pv[nb][r] = e;
          rs += e;
        }
      rs += __shfl_xor(rs, 16);
      rs += __shfl_xor(rs, 32);
      l_run = l_run * alpha + rs;

      // pack P to bf16 pairs: pk[nb][w2] covers j = nb*16 + g*4 + 2*w2 + {0,1}
      uint32_t pk[4][2];
#pragma unroll
      for (int nb = 0; nb < 4; ++nb) {
        pk[nb][0] = (uint32_t)f2bf(pv[nb][0]) | ((uint32_t)f2bf(pv[nb][1]) << 16);
        pk[nb][1] = (uint32_t)f2bf(pv[nb][2]) | ((uint32_t)f2bf(pv[nb][3]) << 16);
      }
#pragma unroll
      for (int nd = 0; nd < 4; ++nd)
#pragma unroll
        for (int r = 0; r < 4; ++r) oacc[nd][r] *= alpha;

      // O^T += V^T P^T : B-frag word W needs pk[2jc+(g>>1)][W&1] from lane ((g&1)*2+(W>>1))*16+q15
#pragma unroll
      for (int jc = 0; jc < 2; ++jc) {
        union { u32x4 u; bf16x8 bvec; } pf;
        const int sgbase = (g & 1) * 2;
#pragma unroll
        for (int W = 0; W < 4; ++W) {
          const int src = (sgbase + (W >> 1)) * 16 + q15;
          const uint32_t lo = (uint32_t)__shfl((int)pk[2 * jc][W & 1], src, 64);
          const uint32_t hi = (uint32_t)__shfl((int)pk[2 * jc + 1][W & 1], src, 64);
          pf.u[W] = (lane >= 32) ? hi : lo;
        }
        __builtin_amdgcn_s_setprio(1);
#pragma unroll
        for (int nd = 0; nd < 4; ++nd) {
          const int rr = nd * 16 + q15;
          const int cc = jc * 4 + g;
          bf16x8 vf = *(const bf16x8*)&bV[rr * 64 + ((cc ^ (rr & 7)) << 3)];
          oacc[nd] = __builtin_amdgcn_mfma_f32_16x16x32_bf16(vf, pf.bvec, oacc[nd], 0, 0, 0);
        }
        __builtin_amdgcn_s_setprio(0);
      }
    }

    // epilogue: lane owns q-row qrow; oacc[nd][r] = O[qrow][nd*16 + g*4 + r]
    const float rl = 1.0f / l_run;
#pragma unroll
    for (int nd = 0; nd < 4; ++nd) {
      ushort4 st;
      st.x = f2bf(oacc[nd][0] * rl);
      st.y = f2bf(oacc[nd][1] * rl);
      st.z = f2bf(oacc[nd][2] * rl);
      st.w = f2bf(oacc[nd][3] * rl);
      *(ushort4*)&attnb[((size_t)(b * SEQ + qrow)) * D_MODEL + h * 64 + nd * 16 + g * 4] = st;
    }
  }
}

// ---------------- launcher ----------------
extern "C" void kernel_launch(void* const* d_in, const int* in_sizes, int n_in,
                              void* d_out, int out_size, void* d_ws, size_t ws_size,
                              hipStream_t stream) {
  (void)in_sizes; (void)n_in; (void)out_size; (void)ws_size;
  const float* Q  = (const float*)d_in[0];
  const float* K  = (const float*)d_in[1];
  const float* V  = (const float*)d_in[2];
  // d_in[3] = mask — causal, implemented analytically
  const float* Wq = (const float*)d_in[4];
  const float* bq = (const float*)d_in[5];
  const float* Wk = (const float*)d_in[6];
  const float* bk = (const float*)d_in[7];
  const float* Wv = (const float*)d_in[8];
  const float* bv = (const float*)d_in[9];
  const float* Wo = (const float*)d_in[10];
  const float* bo = (const float*)d_in[11];

  char* ws = (char*)d_ws;
  size_t off = 0;
  auto carve = [&](size_t bytes) { char* p = ws + off; off += bytes; return p; };
  const size_t szX = (size_t)MTOT * D_MODEL * 2;       // 8 MB
  const size_t szW = (size_t)D_MODEL * D_MODEL * 2;    // 2 MB
  u16* Qb  = (u16*)carve(szX);   // [Qb|Kb|Vb] must stay contiguous (fused GEMM A)
  u16* Kb  = (u16*)carve(szX);
  u16* Vb  = (u16*)carve(szX);
  u16* Wqb = (u16*)carve(szW);
  u16* Wkb = (u16*)carve(szW);
  u16* Wvb = (u16*)carve(szW);
  u16* Wob = (u16*)carve(szW);
  u16* qhB = (u16*)carve(szX);
  u16* khB = (u16*)carve(szX);
  u16* vtB = (u16*)carve(szX);
  u16* attnb = Qb;   // Qb dead after gemm_qkv

  const int nX = MTOT * D_MODEL;
  const int nW = D_MODEL * D_MODEL;
  cast_bf16_kernel<<<nX / 1024, 256, 0, stream>>>(Q,  Qb,  nX);
  cast_bf16_kernel<<<nX / 1024, 256, 0, stream>>>(K,  Kb,  nX);
  cast_bf16_kernel<<<nX / 1024, 256, 0, stream>>>(V,  Vb,  nX);
  cast_bf16_kernel<<<nW / 1024, 256, 0, stream>>>(Wq, Wqb, nW);
  cast_bf16_kernel<<<nW / 1024, 256, 0, stream>>>(Wk, Wkb, nW);
  cast_bf16_kernel<<<nW / 1024, 256, 0, stream>>>(Wv, Wvb, nW);
  cast_bf16_kernel<<<nW / 1024, 256, 0, stream>>>(Wo, Wob, nW);

  gemm_qkv<<<dim3(3 * MTOT / 128, D_MODEL / 128), 256, 0, stream>>>(
      Qb, Wqb, Wkb, Wvb, bq, bk, bv, qhB, khB, vtB);

  attn_kernel<<<dim3(NT / 2, BATCH * NHEADS), 256, 0, stream>>>(qhB, khB, vtB, attnb);

  gemm_out<<<dim3(MTOT / 128, D_MODEL / 128), 256, 0, stream>>>(attnb, Wob, bo, (float*)d_out);
}

// Round 3
// 128.939 us; speedup vs baseline: 2.0862x; 1.1401x over previous
//
#include <hip/hip_runtime.h>
#include <cstdint>
#include <cstddef>

#define D_MODEL 1024
#define NHEADS  16
#define DK      64
#define BATCH   2
#define SEQ     2048
#define MTOT    (BATCH*SEQ)   // 4096
#define NT      (SEQ/64)      // 32

typedef unsigned short u16;
typedef __attribute__((ext_vector_type(8))) __bf16 bf16x8;
typedef __attribute__((ext_vector_type(4))) float  f32x4;
typedef __attribute__((ext_vector_type(4))) uint32_t u32x4;

// softmax scale folded into q-projection: 1/sqrt(64) * log2(e)
#define QSCALE 0.18033688f

static __device__ __forceinline__ void gload16(const void* g, void* l) {
  __builtin_amdgcn_global_load_lds((const __attribute__((address_space(1))) void*)g,
                                   (__attribute__((address_space(3))) void*)l,
                                   16, 0, 0);
}

// ---------------- fused fp32 -> bf16 cast of all 7 tensors ----------------
// dstX = [Qb|Kb|Vb] contiguous (12M elems), dstW = [Wqb|Wkb|Wvb|Wob] contiguous (4M).
__global__ void cast_all_kernel(
    const float* __restrict__ Q, const float* __restrict__ K, const float* __restrict__ V,
    const float* __restrict__ Wq, const float* __restrict__ Wk,
    const float* __restrict__ Wv, const float* __restrict__ Wo,
    u16* __restrict__ dstX, u16* __restrict__ dstW) {
  constexpr int NX = MTOT * D_MODEL;      // 4194304
  constexpr int NW = D_MODEL * D_MODEL;   // 1048576
  const int i = (blockIdx.x * blockDim.x + threadIdx.x) * 4;
  const float* src;
  u16* dst;
  if (i < 3 * NX) {
    dst = dstX + i;
    src = (i < NX) ? Q + i : (i < 2 * NX) ? K + (i - NX) : V + (i - 2 * NX);
  } else {
    const int j = i - 3 * NX;
    dst = dstW + j;
    const int ws = j >> 20;                // NW = 2^20
    const int jo = j & (NW - 1);
    src = (ws == 0) ? Wq + jo : (ws == 1) ? Wk + jo : (ws == 2) ? Wv + jo : Wo + jo;
  }
  float4 f = *reinterpret_cast<const float4*>(src);
  union { __bf16 h[4]; ushort4 s; } o;
  o.h[0] = (__bf16)f.x; o.h[1] = (__bf16)f.y; o.h[2] = (__bf16)f.z; o.h[3] = (__bf16)f.w;
  *reinterpret_cast<ushort4*>(dst) = o.s;
}

// ---------------- fused QKV projection GEMM ----------------
// A = [Qb|Kb|Vb] stacked: [3*4096, 1024] bf16. W sel by m-chunk.
// q (scaled by QSCALE), k -> [B,H,S,DK]; v -> [B,H,DK,S].
__global__ __launch_bounds__(256, 2) void gemm_qkv(
    const u16* __restrict__ A,
    const u16* __restrict__ W0, const u16* __restrict__ W1, const u16* __restrict__ W2,
    const float* __restrict__ b0, const float* __restrict__ b1, const float* __restrict__ b2,
    u16* __restrict__ out_q, u16* __restrict__ out_k, u16* __restrict__ out_v) {
  constexpr int K = 1024;
  __shared__ __align__(16) u16 lA[128 * 64];
  __shared__ __align__(16) u16 lB[128 * 64];
  const int w = threadIdx.x >> 6, lane = threadIdx.x & 63;
  const int blockM = blockIdx.x * 128, blockN = blockIdx.y * 128;
  const int sel = blockIdx.x >> 5;   // 0:q 1:k 2:v
  const u16*  Bt   = sel == 0 ? W0 : (sel == 1 ? W1 : W2);
  const float* bias = sel == 0 ? b0 : (sel == 1 ? b1 : b2);
  const int wm = (w >> 1) * 64, wn = (w & 1) * 64;
  f32x4 acc[4][4] = {};
  for (int kt = 0; kt < K; kt += 64) {
#pragma unroll
    for (int it = 0; it < 4; ++it) {
      int rowb = w * 32 + it * 8;
      int row  = rowb + (lane >> 3);
      int cc   = (lane & 7) * 8;
      gload16(A  + (size_t)(blockM + row) * K + kt + cc, &lA[rowb * 64]);
      gload16(Bt + (size_t)(blockN + row) * K + kt + cc, &lB[rowb * 64]);
    }
    __syncthreads();
#pragma unroll
    for (int kc = 0; kc < 2; ++kc) {
      bf16x8 af[4], bfr[4];
#pragma unroll
      for (int i = 0; i < 4; ++i)
        af[i] = *(const bf16x8*)&lA[(wm + i * 16 + (lane & 15)) * 64 + kc * 32 + (lane >> 4) * 8];
#pragma unroll
      for (int j = 0; j < 4; ++j)
        bfr[j] = *(const bf16x8*)&lB[(wn + j * 16 + (lane & 15)) * 64 + kc * 32 + (lane >> 4) * 8];
#pragma unroll
      for (int i = 0; i < 4; ++i)
#pragma unroll
        for (int j = 0; j < 4; ++j)
          acc[i][j] = __builtin_amdgcn_mfma_f32_16x16x32_bf16(af[i], bfr[j], acc[i][j], 0, 0, 0);
    }
    __syncthreads();
  }
  u16* outqk = sel ? out_k : out_q;
#pragma unroll
  for (int i = 0; i < 4; ++i)
#pragma unroll
    for (int j = 0; j < 4; ++j)
#pragma unroll
      for (int r = 0; r < 4; ++r) {
        int m = blockM + wm + i * 16 + (lane >> 4) * 4 + r;
        int n = blockN + wn + j * 16 + (lane & 15);
        float val = acc[i][j][r] + bias[n];
        if (sel == 0) val *= QSCALE;      // fold softmax scale + log2e into q
        int ml = m & (MTOT - 1);
        int b = ml >> 11, s = ml & (SEQ - 1), h = n >> 6, d = n & (DK - 1);
        u16 bv; { union { __bf16 h2; u16 u; } cv; cv.h2 = (__bf16)val; bv = cv.u; }
        if (sel == 2)
          out_v[(((size_t)(b * NHEADS + h)) * DK + d) * SEQ + s] = bv;
        else
          outqk[(((size_t)(b * NHEADS + h)) * SEQ + s) * DK + d] = bv;
      }
}

// ---------------- output projection GEMM (64x128 tile, fp32 out) ----------------
__global__ __launch_bounds__(256, 2) void gemm_out(
    const u16* __restrict__ A, const u16* __restrict__ Bt,
    const float* __restrict__ bias, float* __restrict__ outp) {
  constexpr int K = 1024, N = 1024;
  __shared__ __align__(16) u16 lA[64 * 64];
  __shared__ __align__(16) u16 lB[128 * 64];
  const int w = threadIdx.x >> 6, lane = threadIdx.x & 63;
  const int blockM = blockIdx.x * 64, blockN = blockIdx.y * 128;
  const int wm = (w >> 1) * 32, wn = (w & 1) * 64;
  f32x4 acc[2][4] = {};
  for (int kt = 0; kt < K; kt += 64) {
#pragma unroll
    for (int it = 0; it < 2; ++it) {
      int rowb = w * 16 + it * 8;
      int row  = rowb + (lane >> 3);
      int cc   = (lane & 7) * 8;
      gload16(A + (size_t)(blockM + row) * K + kt + cc, &lA[rowb * 64]);
    }
#pragma unroll
    for (int it = 0; it < 4; ++it) {
      int rowb = w * 32 + it * 8;
      int row  = rowb + (lane >> 3);
      int cc   = (lane & 7) * 8;
      gload16(Bt + (size_t)(blockN + row) * K + kt + cc, &lB[rowb * 64]);
    }
    __syncthreads();
#pragma unroll
    for (int kc = 0; kc < 2; ++kc) {
      bf16x8 af[2], bfr[4];
#pragma unroll
      for (int i = 0; i < 2; ++i)
        af[i] = *(const bf16x8*)&lA[(wm + i * 16 + (lane & 15)) * 64 + kc * 32 + (lane >> 4) * 8];
#pragma unroll
      for (int j = 0; j < 4; ++j)
        bfr[j] = *(const bf16x8*)&lB[(wn + j * 16 + (lane & 15)) * 64 + kc * 32 + (lane >> 4) * 8];
#pragma unroll
      for (int i = 0; i < 2; ++i)
#pragma unroll
        for (int j = 0; j < 4; ++j)
          acc[i][j] = __builtin_amdgcn_mfma_f32_16x16x32_bf16(af[i], bfr[j], acc[i][j], 0, 0, 0);
    }
    __syncthreads();
  }
#pragma unroll
  for (int i = 0; i < 2; ++i)
#pragma unroll
    for (int j = 0; j < 4; ++j)
#pragma unroll
      for (int r = 0; r < 4; ++r) {
        int m = blockM + wm + i * 16 + (lane >> 4) * 4 + r;
        int n = blockN + wn + j * 16 + (lane & 15);
        outp[(size_t)m * N + n] = acc[i][j][r] + bias[n];
      }
}

// ---------------- causal flash attention ----------------
// Swapped QK^T (scores in log2 domain; q pre-scaled), swizzled LDS, dbuf,
// defer-max, XCD head-clustering.
static __device__ __forceinline__ void stage_kv(
    const u16* kp, const u16* vp, int j0,
    u16* bufK, u16* bufV, int w, int lane) {
  const int rsub = lane >> 3;                 // 0..7
  const int cl = ((lane & 7) ^ rsub) << 3;    // pre-swizzled chunk, u16 units
#pragma unroll
  for (int it = 0; it < 2; ++it) {
    const int rowb = w * 16 + it * 8;
    gload16(kp + (size_t)(j0 + rowb + rsub) * DK + cl, bufK + rowb * 64);
    gload16(vp + (size_t)(rowb + rsub) * SEQ + j0 + cl, bufV + rowb * 64);
  }
}

__global__ __launch_bounds__(256, 4) void attn_kernel(
    const u16* __restrict__ qh, const u16* __restrict__ kh,
    const u16* __restrict__ vt, u16* __restrict__ attnb) {
  __shared__ __align__(16) u16 lKV[2][2][64 * 64];   // [dbuf][K/V] = 32 KiB
  const int w = threadIdx.x >> 6, lane = threadIdx.x & 63;
  const int g = lane >> 4, q15 = lane & 15;
  // XCD clustering: round-robin dispatch -> lid&7 = XCD; give each XCD 4 heads
  const int lid = blockIdx.x;                // 512 blocks
  const int xcd = lid & 7, slot = lid >> 3;
  const int bh  = xcd * 4 + (slot >> 4);     // 4 heads per XCD -> 2MB K/V in L2
  const int qtp = slot & 15;                 // pair index
  const int b = bh >> 4, h = bh & 15;
  const u16* qp = qh + (size_t)bh * SEQ * DK;
  const u16* kp = kh + (size_t)bh * SEQ * DK;
  const u16* vp = vt + (size_t)bh * DK * SEQ;

  for (int pi = 0; pi < 2; ++pi) {
    const int qt = pi ? (NT - 1 - qtp) : qtp;   // paired: 33 tiles/block total
    const int qbase = qt * 64;
    const int qrow = qbase + w * 16 + q15;      // this lane's q-row
    bf16x8 aq[2];
    const u16* qr = qp + (size_t)qrow * DK;
#pragma unroll
    for (int kc = 0; kc < 2; ++kc)
      aq[kc] = *(const bf16x8*)(qr + kc * 32 + g * 8);

    float m_run = -1e30f, l_run = 0.f;
    f32x4 oacc[4] = {};
    const int nt = qt + 1;
    __syncthreads();                            // pass boundary: LDS free
    stage_kv(kp, vp, 0, lKV[0][0], lKV[0][1], w, lane);

    for (int t = 0; t < nt; ++t) {
      __syncthreads();                          // tile t staged; buf cur^1 free
      const int cur = t & 1;
      if (t + 1 < nt)
        stage_kv(kp, vp, (t + 1) * 64, lKV[cur ^ 1][0], lKV[cur ^ 1][1], w, lane);
      const u16* bK = lKV[cur][0];
      const u16* bV = lKV[cur][1];

      // S^T = K Q^T : lane holds col q = q15, rows j = nb*16 + g*4 + r (log2 domain)
      f32x4 sacc[4] = {};
      __builtin_amdgcn_s_setprio(1);
#pragma unroll
      for (int kc = 0; kc < 2; ++kc)
#pragma unroll
        for (int nb = 0; nb < 4; ++nb) {
          const int rr = nb * 16 + q15;
          const int cc = kc * 4 + g;
          bf16x8 kf = *(const bf16x8*)&bK[rr * 64 + ((cc ^ (rr & 7)) << 3)];
          sacc[nb] = __builtin_amdgcn_mfma_f32_16x16x32_bf16(kf, aq[kc], sacc[nb], 0, 0, 0);
        }
      __builtin_amdgcn_s_setprio(0);

      // per-q-row online softmax (lane-local + 2 shfl)
      float pvv[4][4];
      float mx = -1e30f;
      if (t == qt) {                            // diag tile: apply causal mask
#pragma unroll
        for (int nb = 0; nb < 4; ++nb)
#pragma unroll
          for (int r = 0; r < 4; ++r) {
            float s = sacc[nb][r];
            if (t * 64 + nb * 16 + g * 4 + r > qrow) s = -1e30f;
            pvv[nb][r] = s;
            mx = fmaxf(mx, s);
          }
      } else {
#pragma unroll
        for (int nb = 0; nb < 4; ++nb)
#pragma unroll
          for (int r = 0; r < 4; ++r) {
            float s = sacc[nb][r];
            pvv[nb][r] = s;
            mx = fmaxf(mx, s);
          }
      }
      mx = fmaxf(mx, __shfl_xor(mx, 16));
      mx = fmaxf(mx, __shfl_xor(mx, 32));
      if (__any(mx > m_run + 8.0f)) {           // defer-max: rescale only on real growth
        const float mn = fmaxf(m_run, mx);
        const float alpha = __builtin_amdgcn_exp2f(m_run - mn);
        m_run = mn;
        l_run *= alpha;
#pragma unroll
        for (int nd = 0; nd < 4; ++nd)
#pragma unroll
          for (int r = 0; r < 4; ++r) oacc[nd][r] *= alpha;
      }
      float rs = 0.f;
#pragma unroll
      for (int nb = 0; nb < 4; ++nb)
#pragma unroll
        for (int r = 0; r < 4; ++r) {
          float e = __builtin_amdgcn_exp2f(pvv[nb][r] - m_run);
          pvv[nb][r] = e;
          rs += e;
        }
      rs += __shfl_xor(rs, 16);
      rs += __shfl_xor(rs, 32);
      l_run += rs;

      // pack P pairs (compiler emits v_cvt_pk_bf16_f32)
      uint32_t pk[4][2];
#pragma unroll
      for (int nb = 0; nb < 4; ++nb) {
        union { __bf16 h2[2]; uint32_t u; } t0, t1;
        t0.h2[0] = (__bf16)pvv[nb][0]; t0.h2[1] = (__bf16)pvv[nb][1];
        t1.h2[0] = (__bf16)pvv[nb][2]; t1.h2[1] = (__bf16)pvv[nb][3];
        pk[nb][0] = t0.u; pk[nb][1] = t1.u;
      }

      // O^T += V^T P^T : B-frag word W from lane ((g&1)*2+(W>>1))*16+q15
#pragma unroll
      for (int jc = 0; jc < 2; ++jc) {
        union { u32x4 u; bf16x8 bvec; } pf;
        const int sgbase = (g & 1) * 2;
#pragma unroll
        for (int W = 0; W < 4; ++W) {
          const int src = (sgbase + (W >> 1)) * 16 + q15;
          const uint32_t lo = (uint32_t)__shfl((int)pk[2 * jc][W & 1], src, 64);
          const uint32_t hi = (uint32_t)__shfl((int)pk[2 * jc + 1][W & 1], src, 64);
          pf.u[W] = (lane >= 32) ? hi : lo;
        }
        __builtin_amdgcn_s_setprio(1);
#pragma unroll
        for (int nd = 0; nd < 4; ++nd) {
          const int rr = nd * 16 + q15;
          const int cc = jc * 4 + g;
          bf16x8 vf = *(const bf16x8*)&bV[rr * 64 + ((cc ^ (rr & 7)) << 3)];
          oacc[nd] = __builtin_amdgcn_mfma_f32_16x16x32_bf16(vf, pf.bvec, oacc[nd], 0, 0, 0);
        }
        __builtin_amdgcn_s_setprio(0);
      }
    }

    // epilogue: lane owns q-row qrow; oacc[nd][r] = O[qrow][nd*16 + g*4 + r]
    const float rl = 1.0f / l_run;
#pragma unroll
    for (int nd = 0; nd < 4; ++nd) {
      union { __bf16 h4[4]; ushort4 s4; } st;
      st.h4[0] = (__bf16)(oacc[nd][0] * rl);
      st.h4[1] = (__bf16)(oacc[nd][1] * rl);
      st.h4[2] = (__bf16)(oacc[nd][2] * rl);
      st.h4[3] = (__bf16)(oacc[nd][3] * rl);
      *(ushort4*)&attnb[((size_t)(b * SEQ + qrow)) * D_MODEL + h * 64 + nd * 16 + g * 4] = st.s4;
    }
  }
}

// ---------------- launcher ----------------
extern "C" void kernel_launch(void* const* d_in, const int* in_sizes, int n_in,
                              void* d_out, int out_size, void* d_ws, size_t ws_size,
                              hipStream_t stream) {
  (void)in_sizes; (void)n_in; (void)out_size; (void)ws_size;
  const float* Q  = (const float*)d_in[0];
  const float* K  = (const float*)d_in[1];
  const float* V  = (const float*)d_in[2];
  // d_in[3] = mask — causal, implemented analytically
  const float* Wq = (const float*)d_in[4];
  const float* bq = (const float*)d_in[5];
  const float* Wk = (const float*)d_in[6];
  const float* bk = (const float*)d_in[7];
  const float* Wv = (const float*)d_in[8];
  const float* bv = (const float*)d_in[9];
  const float* Wo = (const float*)d_in[10];
  const float* bo = (const float*)d_in[11];

  char* ws = (char*)d_ws;
  size_t off = 0;
  auto carve = [&](size_t bytes) { char* p = ws + off; off += bytes; return p; };
  const size_t szX = (size_t)MTOT * D_MODEL * 2;       // 8 MB
  const size_t szW = (size_t)D_MODEL * D_MODEL * 2;    // 2 MB
  u16* Qb  = (u16*)carve(szX);   // [Qb|Kb|Vb] contiguous (fused GEMM A + fused cast dst)
  u16* Kb  = (u16*)carve(szX);
  u16* Vb  = (u16*)carve(szX);
  u16* Wqb = (u16*)carve(szW);   // [Wqb|Wkb|Wvb|Wob] contiguous (fused cast dst)
  u16* Wkb = (u16*)carve(szW);
  u16* Wvb = (u16*)carve(szW);
  u16* Wob = (u16*)carve(szW);
  u16* qhB = (u16*)carve(szX);
  u16* khB = (u16*)carve(szX);
  u16* vtB = (u16*)carve(szX);
  u16* attnb = Qb;   // Qb dead after gemm_qkv
  (void)Kb; (void)Vb; (void)Wkb; (void)Wvb; (void)Wob;

  const int nTot = 3 * MTOT * D_MODEL + 4 * D_MODEL * D_MODEL;  // 16M elems
  cast_all_kernel<<<nTot / 1024, 256, 0, stream>>>(Q, K, V, Wq, Wk, Wv, Wo, Qb, Wqb);

  gemm_qkv<<<dim3(3 * MTOT / 128, D_MODEL / 128), 256, 0, stream>>>(
      Qb, Wqb, Wkb, Wvb, bq, bk, bv, qhB, khB, vtB);

  attn_kernel<<<(NT / 2) * BATCH * NHEADS, 256, 0, stream>>>(qhB, khB, vtB, attnb);

  gemm_out<<<dim3(MTOT / 64, D_MODEL / 128), 256, 0, stream>>>(attnb, Wob, bo, (float*)d_out);
}

// Round 4
// 121.864 us; speedup vs baseline: 2.2073x; 1.0581x over previous
//
#include <hip/hip_runtime.h>
#include <cstdint>
#include <cstddef>

#define D_MODEL 1024
#define NHEADS  16
#define DK      64
#define BATCH   2
#define SEQ     2048
#define MTOT    (BATCH*SEQ)   // 4096
#define NT      (SEQ/64)      // 32

typedef unsigned short u16;
typedef __attribute__((ext_vector_type(8))) __bf16 bf16x8;
typedef __attribute__((ext_vector_type(4))) float  f32x4;
typedef __attribute__((ext_vector_type(4))) uint32_t u32x4;

// softmax scale folded into q-projection: 1/sqrt(64) * log2(e)
#define QSCALE 0.18033688f

static __device__ __forceinline__ void gload16(const void* g, void* l) {
  __builtin_amdgcn_global_load_lds((const __attribute__((address_space(1))) void*)g,
                                   (__attribute__((address_space(3))) void*)l,
                                   16, 0, 0);
}

// ---------------- fused fp32 -> bf16 cast of all 7 tensors ----------------
__global__ void cast_all_kernel(
    const float* __restrict__ Q, const float* __restrict__ K, const float* __restrict__ V,
    const float* __restrict__ Wq, const float* __restrict__ Wk,
    const float* __restrict__ Wv, const float* __restrict__ Wo,
    u16* __restrict__ dstX, u16* __restrict__ dstW) {
  constexpr int NX = MTOT * D_MODEL;      // 4194304
  constexpr int NW = D_MODEL * D_MODEL;   // 1048576
  const int i = (blockIdx.x * blockDim.x + threadIdx.x) * 4;
  const float* src;
  u16* dst;
  if (i < 3 * NX) {
    dst = dstX + i;
    src = (i < NX) ? Q + i : (i < 2 * NX) ? K + (i - NX) : V + (i - 2 * NX);
  } else {
    const int j = i - 3 * NX;
    dst = dstW + j;
    const int ws = j >> 20;                // NW = 2^20
    const int jo = j & (NW - 1);
    src = (ws == 0) ? Wq + jo : (ws == 1) ? Wk + jo : (ws == 2) ? Wv + jo : Wo + jo;
  }
  float4 f = *reinterpret_cast<const float4*>(src);
  union { __bf16 h[4]; ushort4 s; } o;
  o.h[0] = (__bf16)f.x; o.h[1] = (__bf16)f.y; o.h[2] = (__bf16)f.z; o.h[3] = (__bf16)f.w;
  *reinterpret_cast<ushort4*>(dst) = o.s;
}

// ---------------- fused QKV projection GEMM ----------------
// A = [Qb|Kb|Vb] stacked: [3*4096, 1024] bf16. W sel by m-chunk.
// q (scaled by QSCALE), k -> [B,H,S,DK]; v -> [B,H,DK,S].
__global__ __launch_bounds__(256, 2) void gemm_qkv(
    const u16* __restrict__ A,
    const u16* __restrict__ W0, const u16* __restrict__ W1, const u16* __restrict__ W2,
    const float* __restrict__ b0, const float* __restrict__ b1, const float* __restrict__ b2,
    u16* __restrict__ out_q, u16* __restrict__ out_k, u16* __restrict__ out_v) {
  constexpr int K = 1024;
  __shared__ __align__(16) u16 lA[128 * 64];
  __shared__ __align__(16) u16 lB[128 * 64];
  const int w = threadIdx.x >> 6, lane = threadIdx.x & 63;
  const int blockM = blockIdx.x * 128, blockN = blockIdx.y * 128;
  const int sel = blockIdx.x >> 5;   // 0:q 1:k 2:v
  const u16*  Bt   = sel == 0 ? W0 : (sel == 1 ? W1 : W2);
  const float* bias = sel == 0 ? b0 : (sel == 1 ? b1 : b2);
  const int wm = (w >> 1) * 64, wn = (w & 1) * 64;
  f32x4 acc[4][4] = {};
  for (int kt = 0; kt < K; kt += 64) {
#pragma unroll
    for (int it = 0; it < 4; ++it) {
      int rowb = w * 32 + it * 8;
      int row  = rowb + (lane >> 3);
      int cc   = (lane & 7) * 8;
      gload16(A  + (size_t)(blockM + row) * K + kt + cc, &lA[rowb * 64]);
      gload16(Bt + (size_t)(blockN + row) * K + kt + cc, &lB[rowb * 64]);
    }
    __syncthreads();
#pragma unroll
    for (int kc = 0; kc < 2; ++kc) {
      bf16x8 af[4], bfr[4];
#pragma unroll
      for (int i = 0; i < 4; ++i)
        af[i] = *(const bf16x8*)&lA[(wm + i * 16 + (lane & 15)) * 64 + kc * 32 + (lane >> 4) * 8];
#pragma unroll
      for (int j = 0; j < 4; ++j)
        bfr[j] = *(const bf16x8*)&lB[(wn + j * 16 + (lane & 15)) * 64 + kc * 32 + (lane >> 4) * 8];
#pragma unroll
      for (int i = 0; i < 4; ++i)
#pragma unroll
        for (int j = 0; j < 4; ++j)
          acc[i][j] = __builtin_amdgcn_mfma_f32_16x16x32_bf16(af[i], bfr[j], acc[i][j], 0, 0, 0);
    }
    __syncthreads();
  }
  if (sel == 2) {
    // v^T: pack 4 consecutive-s values -> one ushort4 store (coalesced-ish, 4x fewer instrs)
#pragma unroll
    for (int i = 0; i < 4; ++i)
#pragma unroll
      for (int j = 0; j < 4; ++j) {
        int m0 = blockM + wm + i * 16 + (lane >> 4) * 4;
        int n  = blockN + wn + j * 16 + (lane & 15);
        int ml = m0 & (MTOT - 1);
        int b = ml >> 11, s = ml & (SEQ - 1), h = n >> 6, d = n & (DK - 1);
        union { __bf16 h4[4]; ushort4 s4; } st;
#pragma unroll
        for (int r = 0; r < 4; ++r) st.h4[r] = (__bf16)(acc[i][j][r] + bias[n]);
        *(ushort4*)&out_v[(((size_t)(b * NHEADS + h)) * DK + d) * SEQ + s] = st.s4;
      }
  } else {
    u16* outqk = sel ? out_k : out_q;
#pragma unroll
    for (int i = 0; i < 4; ++i)
#pragma unroll
      for (int j = 0; j < 4; ++j)
#pragma unroll
        for (int r = 0; r < 4; ++r) {
          int m = blockM + wm + i * 16 + (lane >> 4) * 4 + r;
          int n = blockN + wn + j * 16 + (lane & 15);
          float val = acc[i][j][r] + bias[n];
          if (sel == 0) val *= QSCALE;      // fold softmax scale + log2e into q
          int ml = m & (MTOT - 1);
          int b = ml >> 11, s = ml & (SEQ - 1), h = n >> 6, d = n & (DK - 1);
          u16 bv; { union { __bf16 h2; u16 u; } cv; cv.h2 = (__bf16)val; bv = cv.u; }
          outqk[(((size_t)(b * NHEADS + h)) * SEQ + s) * DK + d] = bv;
        }
  }
}

// ---------------- output projection GEMM (64x128 tile, fp32 out) ----------------
__global__ __launch_bounds__(256, 2) void gemm_out(
    const u16* __restrict__ A, const u16* __restrict__ Bt,
    const float* __restrict__ bias, float* __restrict__ outp) {
  constexpr int K = 1024, N = 1024;
  __shared__ __align__(16) u16 lA[64 * 64];
  __shared__ __align__(16) u16 lB[128 * 64];
  const int w = threadIdx.x >> 6, lane = threadIdx.x & 63;
  const int blockM = blockIdx.x * 64, blockN = blockIdx.y * 128;
  const int wm = (w >> 1) * 32, wn = (w & 1) * 64;
  f32x4 acc[2][4] = {};
  for (int kt = 0; kt < K; kt += 64) {
#pragma unroll
    for (int it = 0; it < 2; ++it) {
      int rowb = w * 16 + it * 8;
      int row  = rowb + (lane >> 3);
      int cc   = (lane & 7) * 8;
      gload16(A + (size_t)(blockM + row) * K + kt + cc, &lA[rowb * 64]);
    }
#pragma unroll
    for (int it = 0; it < 4; ++it) {
      int rowb = w * 32 + it * 8;
      int row  = rowb + (lane >> 3);
      int cc   = (lane & 7) * 8;
      gload16(Bt + (size_t)(blockN + row) * K + kt + cc, &lB[rowb * 64]);
    }
    __syncthreads();
#pragma unroll
    for (int kc = 0; kc < 2; ++kc) {
      bf16x8 af[2], bfr[4];
#pragma unroll
      for (int i = 0; i < 2; ++i)
        af[i] = *(const bf16x8*)&lA[(wm + i * 16 + (lane & 15)) * 64 + kc * 32 + (lane >> 4) * 8];
#pragma unroll
      for (int j = 0; j < 4; ++j)
        bfr[j] = *(const bf16x8*)&lB[(wn + j * 16 + (lane & 15)) * 64 + kc * 32 + (lane >> 4) * 8];
#pragma unroll
      for (int i = 0; i < 2; ++i)
#pragma unroll
        for (int j = 0; j < 4; ++j)
          acc[i][j] = __builtin_amdgcn_mfma_f32_16x16x32_bf16(af[i], bfr[j], acc[i][j], 0, 0, 0);
    }
    __syncthreads();
  }
#pragma unroll
  for (int i = 0; i < 2; ++i)
#pragma unroll
    for (int j = 0; j < 4; ++j)
#pragma unroll
      for (int r = 0; r < 4; ++r) {
        int m = blockM + wm + i * 16 + (lane >> 4) * 4 + r;
        int n = blockN + wn + j * 16 + (lane & 15);
        outp[(size_t)m * N + n] = acc[i][j][r] + bias[n];
      }
}

// ---------------- causal flash attention ----------------
// Swapped QK^T (log2 domain, q pre-scaled), swizzled LDS, dbuf, defer-max.
// Grid 1024: one qt per block; per-CU qt-sums balanced by involution perms;
// XCD head clustering (4 heads/XCD -> 2MB K/V in L2).
static __device__ __forceinline__ void stage_kv(
    const u16* kp, const u16* vp, int j0,
    u16* bufK, u16* bufV, int w, int lane) {
  const int rsub = lane >> 3;                 // 0..7
  const int cl = ((lane & 7) ^ rsub) << 3;    // pre-swizzled chunk, u16 units
#pragma unroll
  for (int it = 0; it < 2; ++it) {
    const int rowb = w * 16 + it * 8;
    gload16(kp + (size_t)(j0 + rowb + rsub) * DK + cl, bufK + rowb * 64);
    gload16(vp + (size_t)(rowb + rsub) * SEQ + j0 + cl, bufV + rowb * 64);
  }
}

__global__ __launch_bounds__(256, 4) void attn_kernel(
    const u16* __restrict__ qh, const u16* __restrict__ kh,
    const u16* __restrict__ vt, u16* __restrict__ attnb) {
  __shared__ __align__(16) u16 lKV[2][2][64 * 64];   // [dbuf][K/V] = 32 KiB
  const int w = threadIdx.x >> 6, lane = threadIdx.x & 63;
  const int g = lane >> 4, q15 = lane & 15;
  // lid -> (bh, qt): xcd = lid&7 owns heads xcd*4..xcd*4+3 (L2 clustering).
  // qt = involution perm of CU-slot so each CU's 4 resident blocks sum to 66 tiles.
  const int lid = blockIdx.x;                // 1024 blocks, all co-resident (4/CU)
  const int xcd = lid & 7;
  const int local = lid >> 3;                // 0..127 within XCD
  const int cu = local & 31;                 // CU slot within XCD
  const int p  = local >> 5;                 // 0..3 = which head of this XCD
  const int bh = xcd * 4 + p;
  const int cb = (p & 2) ? ((cu + 8) & 31) : cu;
  const int qt = (p & 1) ? (NT - 1 - cb) : cb;
  const int b = bh >> 4, h = bh & 15;
  const u16* qp = qh + (size_t)bh * SEQ * DK;
  const u16* kp = kh + (size_t)bh * SEQ * DK;
  const u16* vp = vt + (size_t)bh * DK * SEQ;

  const int qbase = qt * 64;
  const int qrow = qbase + w * 16 + q15;      // this lane's q-row
  bf16x8 aq[2];
  const u16* qr = qp + (size_t)qrow * DK;
#pragma unroll
  for (int kc = 0; kc < 2; ++kc)
    aq[kc] = *(const bf16x8*)(qr + kc * 32 + g * 8);

  float m_run = -1e30f, l_run = 0.f;
  f32x4 oacc[4] = {};
  const int nt = qt + 1;
  stage_kv(kp, vp, 0, lKV[0][0], lKV[0][1], w, lane);

  for (int t = 0; t < nt; ++t) {
    __syncthreads();                          // tile t staged; buf cur^1 free
    const int cur = t & 1;
    if (t + 1 < nt)
      stage_kv(kp, vp, (t + 1) * 64, lKV[cur ^ 1][0], lKV[cur ^ 1][1], w, lane);
    const u16* bK = lKV[cur][0];
    const u16* bV = lKV[cur][1];

    // S^T = K Q^T : lane holds col q = q15, rows j = nb*16 + g*4 + r (log2 domain)
    f32x4 sacc[4] = {};
    __builtin_amdgcn_s_setprio(1);
#pragma unroll
    for (int kc = 0; kc < 2; ++kc)
#pragma unroll
      for (int nb = 0; nb < 4; ++nb) {
        const int rr = nb * 16 + q15;
        const int cc = kc * 4 + g;
        bf16x8 kf = *(const bf16x8*)&bK[rr * 64 + ((cc ^ (rr & 7)) << 3)];
        sacc[nb] = __builtin_amdgcn_mfma_f32_16x16x32_bf16(kf, aq[kc], sacc[nb], 0, 0, 0);
      }
    __builtin_amdgcn_s_setprio(0);

    // per-q-row online softmax (lane-local + 2 shfl)
    float pvv[4][4];
    float mx = -1e30f;
    if (t == qt) {                            // diag tile: causal mask
#pragma unroll
      for (int nb = 0; nb < 4; ++nb)
#pragma unroll
        for (int r = 0; r < 4; ++r) {
          float s = sacc[nb][r];
          if (t * 64 + nb * 16 + g * 4 + r > qrow) s = -1e30f;
          pvv[nb][r] = s;
          mx = fmaxf(mx, s);
        }
    } else {
#pragma unroll
      for (int nb = 0; nb < 4; ++nb)
#pragma unroll
        for (int r = 0; r < 4; ++r) {
          float s = sacc[nb][r];
          pvv[nb][r] = s;
          mx = fmaxf(mx, s);
        }
    }
    mx = fmaxf(mx, __shfl_xor(mx, 16));
    mx = fmaxf(mx, __shfl_xor(mx, 32));
    if (__any(mx > m_run + 8.0f)) {           // defer-max
      const float mn = fmaxf(m_run, mx);
      const float alpha = __builtin_amdgcn_exp2f(m_run - mn);
      m_run = mn;
      l_run *= alpha;
#pragma unroll
      for (int nd = 0; nd < 4; ++nd)
#pragma unroll
        for (int r = 0; r < 4; ++r) oacc[nd][r] *= alpha;
    }
    float rs = 0.f;
#pragma unroll
    for (int nb = 0; nb < 4; ++nb)
#pragma unroll
      for (int r = 0; r < 4; ++r) {
        float e = __builtin_amdgcn_exp2f(pvv[nb][r] - m_run);
        pvv[nb][r] = e;
        rs += e;
      }
    rs += __shfl_xor(rs, 16);
    rs += __shfl_xor(rs, 32);
    l_run += rs;

    // pack P pairs (v_cvt_pk_bf16_f32)
    uint32_t pk[4][2];
#pragma unroll
    for (int nb = 0; nb < 4; ++nb) {
      union { __bf16 h2[2]; uint32_t u; } t0, t1;
      t0.h2[0] = (__bf16)pvv[nb][0]; t0.h2[1] = (__bf16)pvv[nb][1];
      t1.h2[0] = (__bf16)pvv[nb][2]; t1.h2[1] = (__bf16)pvv[nb][3];
      pk[nb][0] = t0.u; pk[nb][1] = t1.u;
    }

    // O^T += V^T P^T : B-frag word W from lane ((g&1)*2+(W>>1))*16+q15
#pragma unroll
    for (int jc = 0; jc < 2; ++jc) {
      union { u32x4 u; bf16x8 bvec; } pf;
      const int sgbase = (g & 1) * 2;
#pragma unroll
      for (int W = 0; W < 4; ++W) {
        const int src = (sgbase + (W >> 1)) * 16 + q15;
        const uint32_t lo = (uint32_t)__shfl((int)pk[2 * jc][W & 1], src, 64);
        const uint32_t hi = (uint32_t)__shfl((int)pk[2 * jc + 1][W & 1], src, 64);
        pf.u[W] = (lane >= 32) ? hi : lo;
      }
      __builtin_amdgcn_s_setprio(1);
#pragma unroll
      for (int nd = 0; nd < 4; ++nd) {
        const int rr = nd * 16 + q15;
        const int cc = jc * 4 + g;
        bf16x8 vf = *(const bf16x8*)&bV[rr * 64 + ((cc ^ (rr & 7)) << 3)];
        oacc[nd] = __builtin_amdgcn_mfma_f32_16x16x32_bf16(vf, pf.bvec, oacc[nd], 0, 0, 0);
      }
      __builtin_amdgcn_s_setprio(0);
    }
  }

  // epilogue: lane owns q-row qrow; oacc[nd][r] = O[qrow][nd*16 + g*4 + r]
  const float rl = 1.0f / l_run;
#pragma unroll
  for (int nd = 0; nd < 4; ++nd) {
    union { __bf16 h4[4]; ushort4 s4; } st;
    st.h4[0] = (__bf16)(oacc[nd][0] * rl);
    st.h4[1] = (__bf16)(oacc[nd][1] * rl);
    st.h4[2] = (__bf16)(oacc[nd][2] * rl);
    st.h4[3] = (__bf16)(oacc[nd][3] * rl);
    *(ushort4*)&attnb[((size_t)(b * SEQ + qrow)) * D_MODEL + h * 64 + nd * 16 + g * 4] = st.s4;
  }
}

// ---------------- launcher ----------------
extern "C" void kernel_launch(void* const* d_in, const int* in_sizes, int n_in,
                              void* d_out, int out_size, void* d_ws, size_t ws_size,
                              hipStream_t stream) {
  (void)in_sizes; (void)n_in; (void)out_size; (void)ws_size;
  const float* Q  = (const float*)d_in[0];
  const float* K  = (const float*)d_in[1];
  const float* V  = (const float*)d_in[2];
  // d_in[3] = mask — causal, implemented analytically
  const float* Wq = (const float*)d_in[4];
  const float* bq = (const float*)d_in[5];
  const float* Wk = (const float*)d_in[6];
  const float* bk = (const float*)d_in[7];
  const float* Wv = (const float*)d_in[8];
  const float* bv = (const float*)d_in[9];
  const float* Wo = (const float*)d_in[10];
  const float* bo = (const float*)d_in[11];

  char* ws = (char*)d_ws;
  size_t off = 0;
  auto carve = [&](size_t bytes) { char* p = ws + off; off += bytes; return p; };
  const size_t szX = (size_t)MTOT * D_MODEL * 2;       // 8 MB
  const size_t szW = (size_t)D_MODEL * D_MODEL * 2;    // 2 MB
  u16* Qb  = (u16*)carve(szX);   // [Qb|Kb|Vb] contiguous
  u16* Kb  = (u16*)carve(szX);
  u16* Vb  = (u16*)carve(szX);
  u16* Wqb = (u16*)carve(szW);   // [Wqb|Wkb|Wvb|Wob] contiguous
  u16* Wkb = (u16*)carve(szW);
  u16* Wvb = (u16*)carve(szW);
  u16* Wob = (u16*)carve(szW);
  u16* qhB = (u16*)carve(szX);
  u16* khB = (u16*)carve(szX);
  u16* vtB = (u16*)carve(szX);
  u16* attnb = Qb;   // Qb dead after gemm_qkv
  (void)Kb; (void)Vb; (void)Wkb; (void)Wvb; (void)Wob;

  const int nTot = 3 * MTOT * D_MODEL + 4 * D_MODEL * D_MODEL;  // 16M elems
  cast_all_kernel<<<nTot / 1024, 256, 0, stream>>>(Q, K, V, Wq, Wk, Wv, Wo, Qb, Wqb);

  gemm_qkv<<<dim3(3 * MTOT / 128, D_MODEL / 128), 256, 0, stream>>>(
      Qb, Wqb, Wkb, Wvb, bq, bk, bv, qhB, khB, vtB);

  attn_kernel<<<NT * BATCH * NHEADS, 256, 0, stream>>>(qhB, khB, vtB, attnb);

  gemm_out<<<dim3(MTOT / 64, D_MODEL / 128), 256, 0, stream>>>(attnb, Wob, bo, (float*)d_out);
}